// Round 10
// baseline (110.071 us; speedup 1.0000x reference)
//
#include <hip/hip_runtime.h>
#include <hip/hip_bf16.h>

// SGAT layer, pull-based, bf16 z, MFMA split-bf16 GEMM (barrier-free), group-per-row SpMM.
//   z = [ (x@W) * s ; s ]  with s = attn2 + sqrt(attn2^2+1)   (N x 136, bf16)
//   x@W via 3-term split-bf16 MFMA (~fp32 accuracy); each wave owns 16 nodes x 128 cols,
//   A-fragments straight from global, attn2 reduced fully in-wave -> zero barriers.
//   CSR build: standalone hist+rank, one-kernel lookback scan, atomic-free scatter.
//   16-lane-group-per-row gather, 4 edges in flight, fused normalize/bias epilogue.

#define F 128      // F_OUT * H
#define FP 136     // F_OUT*H + H
#define NH 8
#define SCAN_ELEMS 1024
#define ZS 144     // z staging row stride (ushorts): 288B, 16B-aligned

typedef __attribute__((ext_vector_type(8))) short bf16x8;
typedef __attribute__((ext_vector_type(4))) float f32x4;

static __device__ __forceinline__ unsigned short f2bf(float f) {
    __hip_bfloat16 h = __float2bfloat16(f);   // RNE
    return *(unsigned short*)&h;
}
static __device__ __forceinline__ float bf2f(unsigned short u) {
    return __uint_as_float((unsigned int)u << 16);
}
static __device__ __forceinline__ float bf_lo(unsigned int u) { return __uint_as_float(u << 16); }
static __device__ __forceinline__ float bf_hi(unsigned int u) { return __uint_as_float(u & 0xFFFF0000u); }

// W(128x128 fp32 [k][c]) -> wt[col][(ks*4+lq)*16 + e] = hi, [.. + 8 + e] = lo
// (hi and lo fragment for a lane's K-slice are one contiguous 32B load)
// Also zeroes cnt and the scan flag array.
__global__ __launch_bounds__(256)
void k_prep_w(const float* __restrict__ w, unsigned short* __restrict__ wt,
              int* __restrict__ cnt, int ncnt, int* __restrict__ flagsum)
{
    int idx = blockIdx.x * 256 + threadIdx.x;   // 16384 total
    int col = idx >> 7;
    int k   = idx & 127;
    int ks  = k >> 5;
    int lq  = (k >> 3) & 3;
    int e   = k & 7;
    float v = w[k * F + col];
    unsigned short h = f2bf(v);
    unsigned short lo = f2bf(v - bf2f(h));
    int dst = col * 256 + (ks * 4 + lq) * 16 + e;
    wt[dst]     = h;
    wt[dst + 8] = lo;
    if (idx < 64) flagsum[idx] = 0;
    for (int i = idx; i < ncnt; i += 64 * 256) cnt[i] = 0;
}

// 4 waves x 16 nodes = 64 nodes per block; each wave independent (NO barriers).
// Wave computes its 16 nodes x 128 cols, attn2 in-wave, stages z slab in LDS,
// writes z coalesced (16 rows x 272B contiguous).
__global__ __launch_bounds__(256, 3)
void k_gemm_attn(const float* __restrict__ x, const unsigned short* __restrict__ wt,
                 const float* __restrict__ a2, unsigned short* __restrict__ z, int n)
{
    __shared__ __align__(16) unsigned short zls[64 * ZS];

    const int t  = threadIdx.x;
    const int l  = t & 63;
    const int w  = t >> 6;
    const int lm = l & 15;
    const int lq = l >> 4;
    const int n0 = blockIdx.x * 64 + w * 16;   // wave's node base

    int arow = n0 + lm;
    if (arow >= n) arow = n - 1;                // clamp; outputs masked later
    const float* xrow = x + (long)arow * F;

    float a2v[8];
    #pragma unroll
    for (int cf = 0; cf < 8; ++cf) a2v[cf] = a2[cf * 16 + lm];

    f32x4 acc[8];
    #pragma unroll
    for (int cf = 0; cf < 8; ++cf) acc[cf] = (f32x4){0.f, 0.f, 0.f, 0.f};

    #pragma unroll 2
    for (int ks = 0; ks < 4; ++ks) {
        // A: lane's own row, 8 floats (k = ks*32 + lq*8 + e), convert to hi/lo bf16
        float4 fa = *(const float4*)(xrow + ks * 32 + lq * 8);
        float4 fb = *(const float4*)(xrow + ks * 32 + lq * 8 + 4);
        float fs[8] = {fa.x, fa.y, fa.z, fa.w, fb.x, fb.y, fb.z, fb.w};
        bf16x8 ah, al;
        #pragma unroll
        for (int e = 0; e < 8; ++e) {
            unsigned short h = f2bf(fs[e]);
            ah[e] = (short)h;
            al[e] = (short)f2bf(fs[e] - bf2f(h));
        }
        const unsigned short* wks = wt + (ks * 4 + lq) * 16;
        #pragma unroll
        for (int cf = 0; cf < 8; ++cf) {
            const unsigned short* bp = wks + (cf * 16 + lm) * 256;
            bf16x8 bh = *(const bf16x8*)(bp);       // hi | lo contiguous 32B
            bf16x8 bl = *(const bf16x8*)(bp + 8);
            acc[cf] = __builtin_amdgcn_mfma_f32_16x16x32_bf16(ah, bh, acc[cf], 0, 0, 0);
            acc[cf] = __builtin_amdgcn_mfma_f32_16x16x32_bf16(ah, bl, acc[cf], 0, 0, 0);
            acc[cf] = __builtin_amdgcn_mfma_f32_16x16x32_bf16(al, bh, acc[cf], 0, 0, 0);
        }
    }

    // attn2: head of col cf*16+lm is lm&7; partner cols live in lane lm^8.
    // After xor-8 add, THIS lane holds the full head-sum its own cols need.
    float s4[4];
    #pragma unroll
    for (int r = 0; r < 4; ++r) {
        float pl = 0.f;
        #pragma unroll
        for (int cf = 0; cf < 8; ++cf) pl = fmaf(acc[cf][r], a2v[cf], pl);
        pl += __shfl_xor(pl, 8, 64);
        s4[r] = pl + sqrtf(pl * pl + 1.0f);
    }

    unsigned short* zw = zls + (w * 16) * ZS;   // wave's private slab

    if (lm < 8) {                               // mask cols: head j == lm
        #pragma unroll
        for (int r = 0; r < 4; ++r)
            zw[(lq * 4 + r) * ZS + F + lm] = f2bf(s4[r]);
    }
    #pragma unroll
    for (int cf = 0; cf < 8; ++cf)
        #pragma unroll
        for (int r = 0; r < 4; ++r)
            zw[(lq * 4 + r) * ZS + cf * 16 + lm] = f2bf(acc[cf][r] * s4[r]);

    // coalesced z write: wave's 16 rows x 17 dwordx4 (272B/row, rows contiguous)
    #pragma unroll
    for (int i = 0; i < 5; ++i) {
        int idx = i * 64 + l;
        if (idx < 16 * 17) {
            int row = idx / 17;
            int q   = idx - row * 17;
            int gn  = n0 + row;
            if (gn < n) {
                uint4 v = *(const uint4*)(&zw[row * ZS + q * 8]);
                ((uint4*)(z + (long)gn * FP))[q] = v;
            }
        }
    }
}

// standalone hist + per-edge rank (order within row)
__global__ __launch_bounds__(256)
void k_hist(const int* __restrict__ rows, int* __restrict__ cnt,
            int* __restrict__ rank, int E)
{
    int e = blockIdx.x * blockDim.x + threadIdx.x;
    if (e < E) rank[e] = atomicAdd(&cnt[rows[e]], 1);
}

// one-kernel exclusive scan via decoupled lookback (nblk <= 64 blocks, all resident)
__global__ __launch_bounds__(256)
void k_scan_one(const int* __restrict__ cnt, int* __restrict__ flagsum,
                int* __restrict__ start, int n, int E)
{
    const int b = blockIdx.x;
    const int t = threadIdx.x;
    const int lane = t & 63;
    const int wv = t >> 6;
    const int base = b * SCAN_ELEMS + t * 4;

    int v[4];
    int sum4 = 0;
    #pragma unroll
    for (int k = 0; k < 4; ++k) {
        int i = base + k;
        v[k] = (i < n) ? cnt[i] : 0;
        sum4 += v[k];
    }

    int incl = sum4;
    #pragma unroll
    for (int off = 1; off < 64; off <<= 1) {
        int u = __shfl_up(incl, off, 64);
        if (lane >= off) incl += u;
    }

    __shared__ int waveSums[4];
    __shared__ int boffs_sh;
    if (lane == 63) waveSums[wv] = incl;
    __syncthreads();
    if (t == 0) {
        int r = 0;
        #pragma unroll
        for (int w2 = 0; w2 < 4; ++w2) { int tmp = waveSums[w2]; waveSums[w2] = r; r += tmp; }
        atomicExch(&flagsum[b], r + 1);          // publish packed block total
    }

    if (t < 64) {                                 // lookback over predecessors
        int acc = 0;
        for (int i = lane; i < b; i += 64) {
            int f;
            while ((f = atomicAdd(&flagsum[i], 0)) == 0) { }
            acc += f - 1;
        }
        #pragma unroll
        for (int off = 32; off >= 1; off >>= 1) acc += __shfl_down(acc, off, 64);
        if (t == 0) boffs_sh = acc;
    }
    __syncthreads();

    int run = boffs_sh + waveSums[wv] + (incl - sum4);
    #pragma unroll
    for (int k = 0; k < 4; ++k) {
        int i = base + k;
        if (i < n) start[i] = run;
        run += v[k];
        if (i == n - 1) start[n] = E;   // CSR end pointer
    }
}

// atomic-free scatter: pos = start[row] + rank
__global__ __launch_bounds__(256)
void k_scatter(const int* __restrict__ rows, const int* __restrict__ cols,
               const float* __restrict__ vals, const int* __restrict__ start,
               const int* __restrict__ rank, int2* __restrict__ ce, int E)
{
    int e = blockIdx.x * blockDim.x + threadIdx.x;
    if (e >= E) return;
    int pos = start[rows[e]] + rank[e];
    ce[pos] = make_int2(cols[e], __float_as_int(vals[e]));
}

// one 16-lane group per destination row (4 rows/wave); lane owns 8 bf16 cols;
// 4 edges in flight per group
__global__ __launch_bounds__(256)
void k_spmm_pull(const int* __restrict__ start, const int2* __restrict__ ce,
                 const unsigned short* __restrict__ z, const float* __restrict__ bias,
                 float* __restrict__ out, int n)
{
    const int grp  = (blockIdx.x * blockDim.x + threadIdx.x) >> 4;   // row
    const int lane = threadIdx.x & 63;
    const int c16  = lane & 15;
    if (grp >= n) return;

    const int mq  = c16 & 3;
    const int s0  = start[grp];
    const int end = start[grp + 1];

    float az[8];
    #pragma unroll
    for (int k = 0; k < 8; ++k) az[k] = 0.f;
    float am0 = 0.f, am1 = 0.f;

    for (int e = s0; e < end; e += 4) {
        int e1 = (e + 1 < end) ? e + 1 : end - 1;
        int e2 = (e + 2 < end) ? e + 2 : end - 1;
        int e3 = (e + 3 < end) ? e + 3 : end - 1;
        int2 p0 = ce[e];
        int2 p1 = ce[e1];
        int2 p2 = ce[e2];
        int2 p3 = ce[e3];
        float v0 = __int_as_float(p0.y);
        float v1 = (e + 1 < end) ? __int_as_float(p1.y) : 0.f;
        float v2 = (e + 2 < end) ? __int_as_float(p2.y) : 0.f;
        float v3 = (e + 3 < end) ? __int_as_float(p3.y) : 0.f;
        const unsigned short* b0 = z + (long)p0.x * FP;
        const unsigned short* b1 = z + (long)p1.x * FP;
        const unsigned short* b2 = z + (long)p2.x * FP;
        const unsigned short* b3 = z + (long)p3.x * FP;
        uint4 d0 = *(const uint4*)(b0 + 8 * c16);
        uint4 d1 = *(const uint4*)(b1 + 8 * c16);
        uint4 d2 = *(const uint4*)(b2 + 8 * c16);
        uint4 d3 = *(const uint4*)(b3 + 8 * c16);
        unsigned int m0 = *((const unsigned int*)(b0 + F) + mq);
        unsigned int m1 = *((const unsigned int*)(b1 + F) + mq);
        unsigned int m2 = *((const unsigned int*)(b2 + F) + mq);
        unsigned int m3 = *((const unsigned int*)(b3 + F) + mq);

        az[0] = fmaf(v0, bf_lo(d0.x), az[0]);  az[1] = fmaf(v0, bf_hi(d0.x), az[1]);
        az[2] = fmaf(v0, bf_lo(d0.y), az[2]);  az[3] = fmaf(v0, bf_hi(d0.y), az[3]);
        az[4] = fmaf(v0, bf_lo(d0.z), az[4]);  az[5] = fmaf(v0, bf_hi(d0.z), az[5]);
        az[6] = fmaf(v0, bf_lo(d0.w), az[6]);  az[7] = fmaf(v0, bf_hi(d0.w), az[7]);
        am0   = fmaf(v0, bf_lo(m0), am0);      am1   = fmaf(v0, bf_hi(m0), am1);

        az[0] = fmaf(v1, bf_lo(d1.x), az[0]);  az[1] = fmaf(v1, bf_hi(d1.x), az[1]);
        az[2] = fmaf(v1, bf_lo(d1.y), az[2]);  az[3] = fmaf(v1, bf_hi(d1.y), az[3]);
        az[4] = fmaf(v1, bf_lo(d1.z), az[4]);  az[5] = fmaf(v1, bf_hi(d1.z), az[5]);
        az[6] = fmaf(v1, bf_lo(d1.w), az[6]);  az[7] = fmaf(v1, bf_hi(d1.w), az[7]);
        am0   = fmaf(v1, bf_lo(m1), am0);      am1   = fmaf(v1, bf_hi(m1), am1);

        az[0] = fmaf(v2, bf_lo(d2.x), az[0]);  az[1] = fmaf(v2, bf_hi(d2.x), az[1]);
        az[2] = fmaf(v2, bf_lo(d2.y), az[2]);  az[3] = fmaf(v2, bf_hi(d2.y), az[3]);
        az[4] = fmaf(v2, bf_lo(d2.z), az[4]);  az[5] = fmaf(v2, bf_hi(d2.z), az[5]);
        az[6] = fmaf(v2, bf_lo(d2.w), az[6]);  az[7] = fmaf(v2, bf_hi(d2.w), az[7]);
        am0   = fmaf(v2, bf_lo(m2), am0);      am1   = fmaf(v2, bf_hi(m2), am1);

        az[0] = fmaf(v3, bf_lo(d3.x), az[0]);  az[1] = fmaf(v3, bf_hi(d3.x), az[1]);
        az[2] = fmaf(v3, bf_lo(d3.y), az[2]);  az[3] = fmaf(v3, bf_hi(d3.y), az[3]);
        az[4] = fmaf(v3, bf_lo(d3.z), az[4]);  az[5] = fmaf(v3, bf_hi(d3.z), az[5]);
        az[6] = fmaf(v3, bf_lo(d3.w), az[6]);  az[7] = fmaf(v3, bf_hi(d3.w), az[7]);
        am0   = fmaf(v3, bf_lo(m3), am0);      am1   = fmaf(v3, bf_hi(m3), am1);
    }

    // denominators: lane gb+i holds heads 2i (am0) and 2i+1 (am1)
    const int gb = lane & 48;
    float den[8];
    den[0] = __shfl(am0, gb + 0, 64);  den[1] = __shfl(am1, gb + 0, 64);
    den[2] = __shfl(am0, gb + 1, 64);  den[3] = __shfl(am1, gb + 1, 64);
    den[4] = __shfl(am0, gb + 2, 64);  den[5] = __shfl(am1, gb + 2, 64);
    den[6] = __shfl(am0, gb + 3, 64);  den[7] = __shfl(am1, gb + 3, 64);

    const float* bp = bias + 8 * c16;   // col 8*c16+k has head k
    float4 b0v = *(const float4*)(bp);
    float4 b1v = *(const float4*)(bp + 4);
    float4 o0, o1;
    o0.x = az[0] / (den[0] + 1e-9f) + b0v.x;
    o0.y = az[1] / (den[1] + 1e-9f) + b0v.y;
    o0.z = az[2] / (den[2] + 1e-9f) + b0v.z;
    o0.w = az[3] / (den[3] + 1e-9f) + b0v.w;
    o1.x = az[4] / (den[4] + 1e-9f) + b1v.x;
    o1.y = az[5] / (den[5] + 1e-9f) + b1v.y;
    o1.z = az[6] / (den[6] + 1e-9f) + b1v.z;
    o1.w = az[7] / (den[7] + 1e-9f) + b1v.w;
    float* op = out + (long)grp * F + 8 * c16;
    *(float4*)(op)     = o0;
    *(float4*)(op + 4) = o1;
}

extern "C" void kernel_launch(void* const* d_in, const int* in_sizes, int n_in,
                              void* d_out, int out_size, void* d_ws, size_t ws_size,
                              hipStream_t stream)
{
    const float* x    = (const float*)d_in[0];
    const int*   ei   = (const int*)d_in[1];
    const float* vals = (const float*)d_in[2];
    const float* w    = (const float*)d_in[3];
    const float* bias = (const float*)d_in[4];
    const float* a2   = (const float*)d_in[5];
    float* out = (float*)d_out;

    const int N = in_sizes[0] / F;
    const int E = in_sizes[2];
    const int* rows = ei;
    const int* cols = ei + E;

    const int nblk = (N + SCAN_ELEMS - 1) / SCAN_ELEMS;   // 49 (<=64 required)

    char* p = (char*)d_ws;
    unsigned short* z  = (unsigned short*)p;  p += (((size_t)N * FP * sizeof(unsigned short) + 255) & ~255ull);
    unsigned short* wt = (unsigned short*)p;  p += 128 * 256 * sizeof(unsigned short);
    int*   cnt      = (int*)p;    p += ((size_t)N + 64) * sizeof(int);
    int*   start    = (int*)p;    p += ((size_t)N + 64) * sizeof(int);
    int*   flagsum  = (int*)p;    p += 64 * sizeof(int);
    int*   rank     = (int*)p;    p += (size_t)E * sizeof(int);
    int2*  ce       = (int2*)p;

    k_prep_w<<<dim3(64), dim3(256), 0, stream>>>(w, wt, cnt, N, flagsum);

    dim3 b1(256), g1((N + 63) / 64);
    k_gemm_attn<<<g1, b1, 0, stream>>>(x, wt, a2, z, N);

    k_hist<<<dim3((E + 255) / 256), dim3(256), 0, stream>>>(rows, cnt, rank, E);

    k_scan_one<<<dim3(nblk), dim3(256), 0, stream>>>(cnt, flagsum, start, N, E);

    k_scatter<<<dim3((E + 255) / 256), dim3(256), 0, stream>>>(rows, cols, vals, start, rank, ce, E);

    dim3 b5(256), g5(((size_t)N * 16 + 255) / 256);
    k_spmm_pull<<<g5, b5, 0, stream>>>(start, ce, z, bias, out, N);
}

// Round 11
// 96.657 us; speedup vs baseline: 1.1388x; 1.1388x over previous
//
#include <hip/hip_runtime.h>
#include <hip/hip_bf16.h>

// SGAT layer, pull-based, bf16 z, MFMA split-bf16 GEMM (R9 tiling @ 128-thread blocks).
//   z = [ (x@W) * s ; s ]  with s = attn2 + sqrt(attn2^2+1)   (N x 136, bf16)
//   x@W via 3-term split-bf16 MFMA (~fp32 accuracy). 32 nodes/block, 2 waves;
//   wave owns 64 cols; x staged hi/lo in LDS (coalesced); cross-wave attn2 via part[].
//   CSR build: standalone hist+rank, one-kernel lookback scan, atomic-free scatter.
//   16-lane-group-per-row gather, 4 edges in flight, fused normalize/bias epilogue.

#define F 128      // F_OUT * H
#define FP 136     // F_OUT*H + H
#define NH 8
#define SCAN_ELEMS 1024
#define XS 264     // x staging row stride (ushorts): hi|lo, 16B-aligned
#define ZS 144     // z staging row stride (ushorts): 288B, 16B-aligned
#define GN 32      // nodes per block

typedef __attribute__((ext_vector_type(8))) short bf16x8;
typedef __attribute__((ext_vector_type(4))) float f32x4;

static __device__ __forceinline__ unsigned short f2bf(float f) {
    __hip_bfloat16 h = __float2bfloat16(f);   // RNE
    return *(unsigned short*)&h;
}
static __device__ __forceinline__ float bf2f(unsigned short u) {
    return __uint_as_float((unsigned int)u << 16);
}
static __device__ __forceinline__ float bf_lo(unsigned int u) { return __uint_as_float(u << 16); }
static __device__ __forceinline__ float bf_hi(unsigned int u) { return __uint_as_float(u & 0xFFFF0000u); }

// W(128x128 fp32 [k][c]) -> Wt[col][0:128]=bf16 hi, [128:256]=bf16 residual.
// Also zeroes cnt and the scan flag array (fresh every call).
__global__ __launch_bounds__(256)
void k_prep_w(const float* __restrict__ w, unsigned short* __restrict__ wt,
              int* __restrict__ cnt, int ncnt, int* __restrict__ flagsum)
{
    int idx = blockIdx.x * 256 + threadIdx.x;   // 16384 total
    int col = idx >> 7;
    int k   = idx & 127;
    float v = w[k * F + col];
    unsigned short h = f2bf(v);
    unsigned short lo = f2bf(v - bf2f(h));
    wt[col * 256 + k]       = h;
    wt[col * 256 + 128 + k] = lo;
    if (idx < 64) flagsum[idx] = 0;
    for (int i = idx; i < ncnt; i += 64 * 256) cnt[i] = 0;
}

// 32 nodes x 128 cols per 128-thread block (2 waves); wave w owns cols [w*64, w*64+64).
// LDS ~19.9KB -> 8 blocks/CU.
__global__ __launch_bounds__(128)
void k_gemm_attn(const float* __restrict__ x, const unsigned short* __restrict__ wt,
                 const float* __restrict__ a2, unsigned short* __restrict__ z, int n)
{
    __shared__ __align__(16) unsigned short xls[GN * XS];   // reused as zls later
    __shared__ float part[2 * GN * 8];                      // [wave][node][head]
    __shared__ float sarr[GN * 8];                          // [node][head]

    const int t  = threadIdx.x;
    const int l  = t & 63;
    const int w  = t >> 6;         // wave 0..1
    const int lm = l & 15;
    const int lq = l >> 4;
    const int n0 = blockIdx.x * GN;

    // ---- stage x tile as bf16 hi/lo (coalesced float4 loads) ----
    #pragma unroll
    for (int i = 0; i < 8; ++i) {
        int idx  = i * 128 + t;        // 1024 = 32 nodes x 32 float4
        int node = idx >> 5;
        int k0   = (idx & 31) * 4;
        int gn   = n0 + node;
        float4 v = (gn < n) ? *(const float4*)(x + (long)gn * F + k0)
                            : make_float4(0.f, 0.f, 0.f, 0.f);
        ushort4 h, lo;
        h.x  = f2bf(v.x); h.y  = f2bf(v.y); h.z  = f2bf(v.z); h.w  = f2bf(v.w);
        lo.x = f2bf(v.x - bf2f(h.x));
        lo.y = f2bf(v.y - bf2f(h.y));
        lo.z = f2bf(v.z - bf2f(h.z));
        lo.w = f2bf(v.w - bf2f(h.w));
        *(ushort4*)(&xls[node * XS + k0])       = h;
        *(ushort4*)(&xls[node * XS + 128 + k0]) = lo;
    }
    __syncthreads();

    // ---- MFMA main loop: acc[rf][cf] covers rows rf*16+.., cols w*64+cf*16+.. ----
    const int wc = w * 64;
    f32x4 acc[2][4];
    #pragma unroll
    for (int rf = 0; rf < 2; ++rf)
        #pragma unroll
        for (int cf = 0; cf < 4; ++cf)
            acc[rf][cf] = (f32x4){0.f, 0.f, 0.f, 0.f};

    #pragma unroll
    for (int ks = 0; ks < 4; ++ks) {
        const int koff = ks * 32 + lq * 8;
        bf16x8 bh[4], bl[4];
        #pragma unroll
        for (int cf = 0; cf < 4; ++cf) {
            const unsigned short* bp = wt + (wc + cf * 16 + lm) * 256 + koff;
            bh[cf] = *(const bf16x8*)(bp);
            bl[cf] = *(const bf16x8*)(bp + 128);
        }
        bf16x8 ah[2], al[2];
        #pragma unroll
        for (int rf = 0; rf < 2; ++rf) {
            const unsigned short* ap = &xls[(rf * 16 + lm) * XS + koff];
            ah[rf] = *(const bf16x8*)(ap);
            al[rf] = *(const bf16x8*)(ap + 128);
        }
        #pragma unroll
        for (int rf = 0; rf < 2; ++rf)
            #pragma unroll
            for (int cf = 0; cf < 4; ++cf) {
                acc[rf][cf] = __builtin_amdgcn_mfma_f32_16x16x32_bf16(ah[rf], bh[cf], acc[rf][cf], 0, 0, 0);
                acc[rf][cf] = __builtin_amdgcn_mfma_f32_16x16x32_bf16(ah[rf], bl[cf], acc[rf][cf], 0, 0, 0);
                acc[rf][cf] = __builtin_amdgcn_mfma_f32_16x16x32_bf16(al[rf], bh[cf], acc[rf][cf], 0, 0, 0);
            }
    }

    // ---- attn2 partials: per-lane over own cols, shfl_xor(8) pairs same-head cols ----
    float a2v[4];
    #pragma unroll
    for (int cf = 0; cf < 4; ++cf) a2v[cf] = a2[wc + cf * 16 + lm];
    const int j = l & 7;

    #pragma unroll
    for (int rf = 0; rf < 2; ++rf) {
        #pragma unroll
        for (int r = 0; r < 4; ++r) {
            float pl = 0.f;
            #pragma unroll
            for (int cf = 0; cf < 4; ++cf) pl = fmaf(acc[rf][cf][r], a2v[cf], pl);
            pl += __shfl_xor(pl, 8, 64);
            if ((l & 8) == 0) {
                int node = rf * 16 + lq * 4 + r;
                part[(w * GN + node) * 8 + j] = pl;
            }
        }
    }
    __syncthreads();   // xls no longer read -> reuse as zls

    unsigned short* zls = xls;

    // ---- s = attn2 + sqrt(attn2^2+1); mask cols into LDS z tile ----
    #pragma unroll
    for (int eo = 0; eo < 2; ++eo) {
        int e    = eo * 128 + t;       // 256 = 32 nodes x 8 heads
        int node = e >> 3;
        int jj   = e & 7;
        float ts = part[(0 * GN + node) * 8 + jj] + part[(1 * GN + node) * 8 + jj];
        float s = ts + sqrtf(ts * ts + 1.0f);
        sarr[node * 8 + jj] = s;
        zls[node * ZS + F + jj] = f2bf(s);
    }
    __syncthreads();

    // ---- scale by s[head] into LDS z tile ----
    #pragma unroll
    for (int rf = 0; rf < 2; ++rf) {
        #pragma unroll
        for (int r = 0; r < 4; ++r) {
            int node = rf * 16 + lq * 4 + r;
            float sv = sarr[node * 8 + j];
            #pragma unroll
            for (int cf = 0; cf < 4; ++cf) {
                int c = wc + cf * 16 + lm;
                zls[node * ZS + c] = f2bf(acc[rf][cf][r] * sv);
            }
        }
    }
    __syncthreads();

    // ---- coalesced z write: 32 rows x 17 dwordx4 (272B/row) ----
    #pragma unroll
    for (int i = 0; i < 5; ++i) {
        int idx = i * 128 + t;
        if (idx < GN * 17) {
            int row = idx / 17;
            int q   = idx - row * 17;
            int gn  = n0 + row;
            if (gn < n) {
                uint4 v = *(const uint4*)(&xls[row * ZS + q * 8]);
                ((uint4*)(z + (long)gn * FP))[q] = v;
            }
        }
    }
}

// standalone hist + per-edge rank (order within row)
__global__ __launch_bounds__(256)
void k_hist(const int* __restrict__ rows, int* __restrict__ cnt,
            int* __restrict__ rank, int E)
{
    int e = blockIdx.x * blockDim.x + threadIdx.x;
    if (e < E) rank[e] = atomicAdd(&cnt[rows[e]], 1);
}

// one-kernel exclusive scan via decoupled lookback (nblk <= 64 blocks, all resident)
__global__ __launch_bounds__(256)
void k_scan_one(const int* __restrict__ cnt, int* __restrict__ flagsum,
                int* __restrict__ start, int n, int E)
{
    const int b = blockIdx.x;
    const int t = threadIdx.x;
    const int lane = t & 63;
    const int wv = t >> 6;
    const int base = b * SCAN_ELEMS + t * 4;

    int v[4];
    int sum4 = 0;
    #pragma unroll
    for (int k = 0; k < 4; ++k) {
        int i = base + k;
        v[k] = (i < n) ? cnt[i] : 0;
        sum4 += v[k];
    }

    int incl = sum4;
    #pragma unroll
    for (int off = 1; off < 64; off <<= 1) {
        int u = __shfl_up(incl, off, 64);
        if (lane >= off) incl += u;
    }

    __shared__ int waveSums[4];
    __shared__ int boffs_sh;
    if (lane == 63) waveSums[wv] = incl;
    __syncthreads();
    if (t == 0) {
        int r = 0;
        #pragma unroll
        for (int w2 = 0; w2 < 4; ++w2) { int tmp = waveSums[w2]; waveSums[w2] = r; r += tmp; }
        atomicExch(&flagsum[b], r + 1);          // publish packed block total
    }

    if (t < 64) {                                 // lookback over predecessors
        int acc = 0;
        for (int i = lane; i < b; i += 64) {
            int f;
            while ((f = atomicAdd(&flagsum[i], 0)) == 0) { }
            acc += f - 1;
        }
        #pragma unroll
        for (int off = 32; off >= 1; off >>= 1) acc += __shfl_down(acc, off, 64);
        if (t == 0) boffs_sh = acc;
    }
    __syncthreads();

    int run = boffs_sh + waveSums[wv] + (incl - sum4);
    #pragma unroll
    for (int k = 0; k < 4; ++k) {
        int i = base + k;
        if (i < n) start[i] = run;
        run += v[k];
        if (i == n - 1) start[n] = E;   // CSR end pointer
    }
}

// atomic-free scatter: pos = start[row] + rank
__global__ __launch_bounds__(256)
void k_scatter(const int* __restrict__ rows, const int* __restrict__ cols,
               const float* __restrict__ vals, const int* __restrict__ start,
               const int* __restrict__ rank, int2* __restrict__ ce, int E)
{
    int e = blockIdx.x * blockDim.x + threadIdx.x;
    if (e >= E) return;
    int pos = start[rows[e]] + rank[e];
    ce[pos] = make_int2(cols[e], __float_as_int(vals[e]));
}

// one 16-lane group per destination row (4 rows/wave); lane owns 8 bf16 cols;
// 4 edges in flight per group
__global__ __launch_bounds__(256)
void k_spmm_pull(const int* __restrict__ start, const int2* __restrict__ ce,
                 const unsigned short* __restrict__ z, const float* __restrict__ bias,
                 float* __restrict__ out, int n)
{
    const int grp  = (blockIdx.x * blockDim.x + threadIdx.x) >> 4;   // row
    const int lane = threadIdx.x & 63;
    const int c16  = lane & 15;
    if (grp >= n) return;

    const int mq  = c16 & 3;
    const int s0  = start[grp];
    const int end = start[grp + 1];

    float az[8];
    #pragma unroll
    for (int k = 0; k < 8; ++k) az[k] = 0.f;
    float am0 = 0.f, am1 = 0.f;

    for (int e = s0; e < end; e += 4) {
        int e1 = (e + 1 < end) ? e + 1 : end - 1;
        int e2 = (e + 2 < end) ? e + 2 : end - 1;
        int e3 = (e + 3 < end) ? e + 3 : end - 1;
        int2 p0 = ce[e];
        int2 p1 = ce[e1];
        int2 p2 = ce[e2];
        int2 p3 = ce[e3];
        float v0 = __int_as_float(p0.y);
        float v1 = (e + 1 < end) ? __int_as_float(p1.y) : 0.f;
        float v2 = (e + 2 < end) ? __int_as_float(p2.y) : 0.f;
        float v3 = (e + 3 < end) ? __int_as_float(p3.y) : 0.f;
        const unsigned short* b0 = z + (long)p0.x * FP;
        const unsigned short* b1 = z + (long)p1.x * FP;
        const unsigned short* b2 = z + (long)p2.x * FP;
        const unsigned short* b3 = z + (long)p3.x * FP;
        uint4 d0 = *(const uint4*)(b0 + 8 * c16);
        uint4 d1 = *(const uint4*)(b1 + 8 * c16);
        uint4 d2 = *(const uint4*)(b2 + 8 * c16);
        uint4 d3 = *(const uint4*)(b3 + 8 * c16);
        unsigned int m0 = *((const unsigned int*)(b0 + F) + mq);
        unsigned int m1 = *((const unsigned int*)(b1 + F) + mq);
        unsigned int m2 = *((const unsigned int*)(b2 + F) + mq);
        unsigned int m3 = *((const unsigned int*)(b3 + F) + mq);

        az[0] = fmaf(v0, bf_lo(d0.x), az[0]);  az[1] = fmaf(v0, bf_hi(d0.x), az[1]);
        az[2] = fmaf(v0, bf_lo(d0.y), az[2]);  az[3] = fmaf(v0, bf_hi(d0.y), az[3]);
        az[4] = fmaf(v0, bf_lo(d0.z), az[4]);  az[5] = fmaf(v0, bf_hi(d0.z), az[5]);
        az[6] = fmaf(v0, bf_lo(d0.w), az[6]);  az[7] = fmaf(v0, bf_hi(d0.w), az[7]);
        am0   = fmaf(v0, bf_lo(m0), am0);      am1   = fmaf(v0, bf_hi(m0), am1);

        az[0] = fmaf(v1, bf_lo(d1.x), az[0]);  az[1] = fmaf(v1, bf_hi(d1.x), az[1]);
        az[2] = fmaf(v1, bf_lo(d1.y), az[2]);  az[3] = fmaf(v1, bf_hi(d1.y), az[3]);
        az[4] = fmaf(v1, bf_lo(d1.z), az[4]);  az[5] = fmaf(v1, bf_hi(d1.z), az[5]);
        az[6] = fmaf(v1, bf_lo(d1.w), az[6]);  az[7] = fmaf(v1, bf_hi(d1.w), az[7]);
        am0   = fmaf(v1, bf_lo(m1), am0);      am1   = fmaf(v1, bf_hi(m1), am1);

        az[0] = fmaf(v2, bf_lo(d2.x), az[0]);  az[1] = fmaf(v2, bf_hi(d2.x), az[1]);
        az[2] = fmaf(v2, bf_lo(d2.y), az[2]);  az[3] = fmaf(v2, bf_hi(d2.y), az[3]);
        az[4] = fmaf(v2, bf_lo(d2.z), az[4]);  az[5] = fmaf(v2, bf_hi(d2.z), az[5]);
        az[6] = fmaf(v2, bf_lo(d2.w), az[6]);  az[7] = fmaf(v2, bf_hi(d2.w), az[7]);
        am0   = fmaf(v2, bf_lo(m2), am0);      am1   = fmaf(v2, bf_hi(m2), am1);

        az[0] = fmaf(v3, bf_lo(d3.x), az[0]);  az[1] = fmaf(v3, bf_hi(d3.x), az[1]);
        az[2] = fmaf(v3, bf_lo(d3.y), az[2]);  az[3] = fmaf(v3, bf_hi(d3.y), az[3]);
        az[4] = fmaf(v3, bf_lo(d3.z), az[4]);  az[5] = fmaf(v3, bf_hi(d3.z), az[5]);
        az[6] = fmaf(v3, bf_lo(d3.w), az[6]);  az[7] = fmaf(v3, bf_hi(d3.w), az[7]);
        am0   = fmaf(v3, bf_lo(m3), am0);      am1   = fmaf(v3, bf_hi(m3), am1);
    }

    // denominators: lane gb+i holds heads 2i (am0) and 2i+1 (am1)
    const int gb = lane & 48;
    float den[8];
    den[0] = __shfl(am0, gb + 0, 64);  den[1] = __shfl(am1, gb + 0, 64);
    den[2] = __shfl(am0, gb + 1, 64);  den[3] = __shfl(am1, gb + 1, 64);
    den[4] = __shfl(am0, gb + 2, 64);  den[5] = __shfl(am1, gb + 2, 64);
    den[6] = __shfl(am0, gb + 3, 64);  den[7] = __shfl(am1, gb + 3, 64);

    const float* bp = bias + 8 * c16;   // col 8*c16+k has head k
    float4 b0v = *(const float4*)(bp);
    float4 b1v = *(const float4*)(bp + 4);
    float4 o0, o1;
    o0.x = az[0] / (den[0] + 1e-9f) + b0v.x;
    o0.y = az[1] / (den[1] + 1e-9f) + b0v.y;
    o0.z = az[2] / (den[2] + 1e-9f) + b0v.z;
    o0.w = az[3] / (den[3] + 1e-9f) + b0v.w;
    o1.x = az[4] / (den[4] + 1e-9f) + b1v.x;
    o1.y = az[5] / (den[5] + 1e-9f) + b1v.y;
    o1.z = az[6] / (den[6] + 1e-9f) + b1v.z;
    o1.w = az[7] / (den[7] + 1e-9f) + b1v.w;
    float* op = out + (long)grp * F + 8 * c16;
    *(float4*)(op)     = o0;
    *(float4*)(op + 4) = o1;
}

extern "C" void kernel_launch(void* const* d_in, const int* in_sizes, int n_in,
                              void* d_out, int out_size, void* d_ws, size_t ws_size,
                              hipStream_t stream)
{
    const float* x    = (const float*)d_in[0];
    const int*   ei   = (const int*)d_in[1];
    const float* vals = (const float*)d_in[2];
    const float* w    = (const float*)d_in[3];
    const float* bias = (const float*)d_in[4];
    const float* a2   = (const float*)d_in[5];
    float* out = (float*)d_out;

    const int N = in_sizes[0] / F;
    const int E = in_sizes[2];
    const int* rows = ei;
    const int* cols = ei + E;

    const int nblk = (N + SCAN_ELEMS - 1) / SCAN_ELEMS;   // 49 (<=64 required)

    char* p = (char*)d_ws;
    unsigned short* z  = (unsigned short*)p;  p += (((size_t)N * FP * sizeof(unsigned short) + 255) & ~255ull);
    unsigned short* wt = (unsigned short*)p;  p += 128 * 256 * sizeof(unsigned short);
    int*   cnt      = (int*)p;    p += ((size_t)N + 64) * sizeof(int);
    int*   start    = (int*)p;    p += ((size_t)N + 64) * sizeof(int);
    int*   flagsum  = (int*)p;    p += 64 * sizeof(int);
    int*   rank     = (int*)p;    p += (size_t)E * sizeof(int);
    int2*  ce       = (int2*)p;

    k_prep_w<<<dim3(64), dim3(256), 0, stream>>>(w, wt, cnt, N, flagsum);

    dim3 b1(128), g1((N + GN - 1) / GN);
    k_gemm_attn<<<g1, b1, 0, stream>>>(x, wt, a2, z, N);

    k_hist<<<dim3((E + 255) / 256), dim3(256), 0, stream>>>(rows, cnt, rank, E);

    k_scan_one<<<dim3(nblk), dim3(256), 0, stream>>>(cnt, flagsum, start, N, E);

    k_scatter<<<dim3((E + 255) / 256), dim3(256), 0, stream>>>(rows, cols, vals, start, rank, ce, E);

    dim3 b5(256), g5(((size_t)N * 16 + 255) / 256);
    k_spmm_pull<<<g5, b5, 0, stream>>>(start, ce, z, bias, out, N);
}